// Round 1
// baseline (341.366 us; speedup 1.0000x reference)
//
#include <hip/hip_runtime.h>
#include <hip/hip_bf16.h>
#include <cmath>

#define T_SEQ 2048
#define D_MODEL 1024
#define NHEAD 16
#define DK 64

typedef short bf16x8 __attribute__((ext_vector_type(8)));
typedef float f32x4 __attribute__((ext_vector_type(4)));

// RNE float -> bf16 (finite inputs only)
__device__ __forceinline__ short f2b(float f) {
    unsigned u = __builtin_bit_cast(unsigned, f);
    unsigned r = (u + 0x7FFFu + ((u >> 16) & 1u)) >> 16;
    return (short)r;
}

// ---------------- fp32 -> bf16 convert (vectorized) ----------------
__global__ __launch_bounds__(256) void cvt_bf16(const float* __restrict__ in,
                                                short* __restrict__ out, int n8) {
    int i = blockIdx.x * blockDim.x + threadIdx.x;
    if (i >= n8) return;
    float4 a = reinterpret_cast<const float4*>(in)[2 * i];
    float4 b = reinterpret_cast<const float4*>(in)[2 * i + 1];
    bf16x8 v;
    v[0] = f2b(a.x); v[1] = f2b(a.y); v[2] = f2b(a.z); v[3] = f2b(a.w);
    v[4] = f2b(b.x); v[5] = f2b(b.y); v[6] = f2b(b.z); v[7] = f2b(b.w);
    reinterpret_cast<bf16x8*>(out)[i] = v;
}

// ---------------- RoPE cos/sin tables: (B*T, 32) ----------------
__global__ __launch_bounds__(256) void rope_table(const int* __restrict__ pos,
                                                  float* __restrict__ ct,
                                                  float* __restrict__ st) {
    int i = blockIdx.x * blockDim.x + threadIdx.x;   // B*T*32 threads
    int bt = i >> 5, n = i & 31;
    float p = (float)pos[bt];
    // inv_freq = 10000^(-2n/64) = exp(-(2n/64)*ln(10000))
    float invf = expf((float)n * (-2.0f / (float)DK) * 9.210340371976184f);
    float ang = p * invf;
    float s, c;
    sincosf(ang, &s, &c);
    ct[i] = c; st[i] = s;
}

// ---------------- GEMM1: qkv = x * W_qkv^T, fused RoPE, scatter ----------------
// A = xb (4096 x 1024 bf16 row-major), B = wqkvb (3072 x 1024 bf16, i.e. N x K)
// 64x64 block tile, 4 waves, wave w owns 16 M-rows x 64 N-cols.
__global__ __launch_bounds__(256) void gemm_qkv(const short* __restrict__ xb,
                                                const short* __restrict__ wb,
                                                const float* __restrict__ ct,
                                                const float* __restrict__ st,
                                                short* __restrict__ Qo,
                                                short* __restrict__ Ko,
                                                short* __restrict__ Vt) {
    __shared__ short As[64][40];
    __shared__ short Bs[64][40];
    const int bm = blockIdx.y * 64, bn = blockIdx.x * 64;
    const int tid = threadIdx.x;
    const int w = tid >> 6, l = tid & 63, lg = l >> 4, li = l & 15;
    const int srow = tid >> 2, scg = (tid & 3) * 8;

    f32x4 zero = {0.f, 0.f, 0.f, 0.f};
    f32x4 acc[4] = {zero, zero, zero, zero};

    for (int k0 = 0; k0 < D_MODEL; k0 += 32) {
        *reinterpret_cast<bf16x8*>(&As[srow][scg]) =
            *reinterpret_cast<const bf16x8*>(&xb[(size_t)(bm + srow) * D_MODEL + k0 + scg]);
        *reinterpret_cast<bf16x8*>(&Bs[srow][scg]) =
            *reinterpret_cast<const bf16x8*>(&wb[(size_t)(bn + srow) * D_MODEL + k0 + scg]);
        __syncthreads();
        bf16x8 a = *reinterpret_cast<const bf16x8*>(&As[w * 16 + li][lg * 8]);
#pragma unroll
        for (int cb = 0; cb < 4; ++cb) {
            bf16x8 b = *reinterpret_cast<const bf16x8*>(&Bs[cb * 16 + li][lg * 8]);
            acc[cb] = __builtin_amdgcn_mfma_f32_16x16x32_bf16(a, b, acc[cb], 0, 0, 0);
        }
        __syncthreads();
    }

    // epilogue: o = bn + cb*16 + li ; block covers exactly one (which, head)
    const int which = blockIdx.x >> 4;   // 0:q 1:k 2:v
    const int h = blockIdx.x & 15;
#pragma unroll
    for (int cb = 0; cb < 4; ++cb) {
        const int d = cb * 16 + li;
#pragma unroll
        for (int r = 0; r < 4; ++r) {
            const int m = bm + w * 16 + lg * 4 + r;       // = b*T + t
            const int b = m >> 11, t = m & (T_SEQ - 1);
            float v = acc[cb][r];
            if (which == 2) {
                // V transposed: Vt[(b*H + h)*DK + d][t]
                Vt[((size_t)((b * NHEAD + h) * DK + d)) * T_SEQ + t] = f2b(v);
            } else {
                float vp = __shfl_xor(v, 1);              // partner of the RoPE pair
                int n = d >> 1;
                float c = ct[(size_t)m * 32 + n];
                float s = st[(size_t)m * 32 + n];
                float o = (d & 1) ? (v * c + vp * s) : (v * c - vp * s);
                short* dst = (which == 0) ? Qo : Ko;
                dst[((size_t)((b * NHEAD + h) * T_SEQ + t)) * DK + d] = f2b(o);
            }
        }
    }
}

// ---------------- flash attention (causal) ----------------
// grid: (T/64, B*H). 4 waves; wave w owns q rows [qb + 16w, qb + 16w + 16).
__global__ __launch_bounds__(256) void attn(const short* __restrict__ Q,
                                            const short* __restrict__ K,
                                            const short* __restrict__ Vt,
                                            short* __restrict__ Cc) {
    __shared__ short Pls[4][16][40];
    const int bh = blockIdx.y;
    const int qb = blockIdx.x * 64;
    const int tid = threadIdx.x;
    const int w = tid >> 6, l = tid & 63, lg = l >> 4, li = l & 15;

    const short* Qh = Q + (size_t)bh * T_SEQ * DK;
    const short* Kh = K + (size_t)bh * T_SEQ * DK;
    const short* Vh = Vt + (size_t)bh * DK * T_SEQ;

    const int q0 = qb + w * 16;
    bf16x8 qf0 = *reinterpret_cast<const bf16x8*>(&Qh[(size_t)(q0 + li) * DK + lg * 8]);
    bf16x8 qf1 = *reinterpret_cast<const bf16x8*>(&Qh[(size_t)(q0 + li) * DK + 32 + lg * 8]);

    f32x4 zero = {0.f, 0.f, 0.f, 0.f};
    f32x4 oacc[4] = {zero, zero, zero, zero};
    float mrun[4] = {-INFINITY, -INFINITY, -INFINITY, -INFINITY};
    float lrun[4] = {0.f, 0.f, 0.f, 0.f};

    const int kv_end = q0 + 16;   // exclusive causal bound for this wave's rows
    for (int n0 = 0; n0 < kv_end; n0 += 32) {
        float sv[2][4];
#pragma unroll
        for (int sub = 0; sub < 2; ++sub) {
            const int nb = n0 + sub * 16;
            if (nb < kv_end) {
                f32x4 s = zero;
                bf16x8 kf0 = *reinterpret_cast<const bf16x8*>(&Kh[(size_t)(nb + li) * DK + lg * 8]);
                bf16x8 kf1 = *reinterpret_cast<const bf16x8*>(&Kh[(size_t)(nb + li) * DK + 32 + lg * 8]);
                s = __builtin_amdgcn_mfma_f32_16x16x32_bf16(qf0, kf0, s, 0, 0, 0);
                s = __builtin_amdgcn_mfma_f32_16x16x32_bf16(qf1, kf1, s, 0, 0, 0);
#pragma unroll
                for (int r = 0; r < 4; ++r) {
                    int qrow = q0 + lg * 4 + r;
                    int kv = nb + li;
                    sv[sub][r] = (kv <= qrow) ? s[r] * 0.125f : -INFINITY;
                }
            } else {
#pragma unroll
                for (int r = 0; r < 4; ++r) sv[sub][r] = -INFINITY;
            }
        }
        // row max over the 16-lane group
        float tm[4];
#pragma unroll
        for (int r = 0; r < 4; ++r) tm[r] = fmaxf(sv[0][r], sv[1][r]);
#pragma unroll
        for (int off = 1; off < 16; off <<= 1)
#pragma unroll
            for (int r = 0; r < 4; ++r) tm[r] = fmaxf(tm[r], __shfl_xor(tm[r], off));

        float alpha[4], rs[4];
#pragma unroll
        for (int r = 0; r < 4; ++r) {
            float mn = fmaxf(mrun[r], tm[r]);
            alpha[r] = __expf(mrun[r] - mn);
            mrun[r] = mn;
            rs[r] = 0.f;
        }
#pragma unroll
        for (int sub = 0; sub < 2; ++sub)
#pragma unroll
            for (int r = 0; r < 4; ++r) {
                float p = __expf(sv[sub][r] - mrun[r]);   // exp(-inf - m) = 0 for masked
                rs[r] += p;
                Pls[w][lg * 4 + r][sub * 16 + li] = f2b(p);
            }
#pragma unroll
        for (int off = 1; off < 16; off <<= 1)
#pragma unroll
            for (int r = 0; r < 4; ++r) rs[r] += __shfl_xor(rs[r], off);
#pragma unroll
        for (int r = 0; r < 4; ++r) lrun[r] = lrun[r] * alpha[r] + rs[r];
#pragma unroll
        for (int cb = 0; cb < 4; ++cb)
#pragma unroll
            for (int r = 0; r < 4; ++r) oacc[cb][r] *= alpha[r];

        // PV: A = P (16x32 from LDS), B = V^T fragments (contiguous from Vt)
        bf16x8 pf = *reinterpret_cast<const bf16x8*>(&Pls[w][li][lg * 8]);
        int kcol = n0 + lg * 8;
        if (kcol > T_SEQ - 8) kcol = T_SEQ - 8;           // clamp (P==0 there anyway)
#pragma unroll
        for (int cb = 0; cb < 4; ++cb) {
            bf16x8 vf = *reinterpret_cast<const bf16x8*>(&Vh[(size_t)(cb * 16 + li) * T_SEQ + kcol]);
            oacc[cb] = __builtin_amdgcn_mfma_f32_16x16x32_bf16(pf, vf, oacc[cb], 0, 0, 0);
        }
    }

    // epilogue: normalize and write concat (B, T, H*dk) as bf16
    const int b = bh >> 4, h = bh & 15;
#pragma unroll
    for (int cb = 0; cb < 4; ++cb)
#pragma unroll
        for (int r = 0; r < 4; ++r) {
            int t = q0 + lg * 4 + r;
            int d = cb * 16 + li;
            float o = oacc[cb][r] / lrun[r];
            Cc[((size_t)(b * T_SEQ + t)) * D_MODEL + h * DK + d] = f2b(o);
        }
}

// ---------------- GEMM2: out = concat * W_out^T (fp32 store) ----------------
__global__ __launch_bounds__(256) void gemm_out(const short* __restrict__ ab,
                                                const short* __restrict__ wb,
                                                float* __restrict__ out) {
    __shared__ short As[64][40];
    __shared__ short Bs[64][40];
    const int bm = blockIdx.y * 64, bn = blockIdx.x * 64;
    const int tid = threadIdx.x;
    const int w = tid >> 6, l = tid & 63, lg = l >> 4, li = l & 15;
    const int srow = tid >> 2, scg = (tid & 3) * 8;

    f32x4 zero = {0.f, 0.f, 0.f, 0.f};
    f32x4 acc[4] = {zero, zero, zero, zero};

    for (int k0 = 0; k0 < D_MODEL; k0 += 32) {
        *reinterpret_cast<bf16x8*>(&As[srow][scg]) =
            *reinterpret_cast<const bf16x8*>(&ab[(size_t)(bm + srow) * D_MODEL + k0 + scg]);
        *reinterpret_cast<bf16x8*>(&Bs[srow][scg]) =
            *reinterpret_cast<const bf16x8*>(&wb[(size_t)(bn + srow) * D_MODEL + k0 + scg]);
        __syncthreads();
        bf16x8 a = *reinterpret_cast<const bf16x8*>(&As[w * 16 + li][lg * 8]);
#pragma unroll
        for (int cb = 0; cb < 4; ++cb) {
            bf16x8 b = *reinterpret_cast<const bf16x8*>(&Bs[cb * 16 + li][lg * 8]);
            acc[cb] = __builtin_amdgcn_mfma_f32_16x16x32_bf16(a, b, acc[cb], 0, 0, 0);
        }
        __syncthreads();
    }
#pragma unroll
    for (int cb = 0; cb < 4; ++cb)
#pragma unroll
        for (int r = 0; r < 4; ++r) {
            const int m = bm + w * 16 + lg * 4 + r;
            out[(size_t)m * D_MODEL + bn + cb * 16 + li] = acc[cb][r];
        }
}

extern "C" void kernel_launch(void* const* d_in, const int* in_sizes, int n_in,
                              void* d_out, int out_size, void* d_ws, size_t ws_size,
                              hipStream_t stream) {
    const float* x    = (const float*)d_in[0];
    const int*   pos  = (const int*)d_in[1];
    const float* wqkv = (const float*)d_in[2];
    const float* wout = (const float*)d_in[3];
    float* out = (float*)d_out;

    char* ws = (char*)d_ws;
    size_t off = 0;
    short* xb  = (short*)(ws + off); off += (size_t)4096 * 1024 * 2;   // 8 MB
    short* wqb = (short*)(ws + off); off += (size_t)3072 * 1024 * 2;   // 6 MB
    short* wob = (short*)(ws + off); off += (size_t)1024 * 1024 * 2;   // 2 MB
    short* Q   = (short*)(ws + off); off += (size_t)32 * 2048 * 64 * 2; // 8 MB
    short* Kb  = (short*)(ws + off); off += (size_t)32 * 2048 * 64 * 2; // 8 MB
    short* Vt  = (short*)(ws + off); off += (size_t)32 * 64 * 2048 * 2; // 8 MB
    off += 4096;                                                        // guard
    short* Cc  = (short*)(ws + off); off += (size_t)4096 * 1024 * 2;   // 8 MB
    float* ct  = (float*)(ws + off); off += (size_t)4096 * 32 * 4;     // 0.5 MB
    float* st  = (float*)(ws + off); off += (size_t)4096 * 32 * 4;     // 0.5 MB
    // total ~51.4 MB of ws

    cvt_bf16<<<2048, 256, 0, stream>>>(x,    xb,  4194304 / 8);
    cvt_bf16<<<1536, 256, 0, stream>>>(wqkv, wqb, 3145728 / 8);
    cvt_bf16<<<512,  256, 0, stream>>>(wout, wob, 1048576 / 8);
    rope_table<<<512, 256, 0, stream>>>(pos, ct, st);
    gemm_qkv<<<dim3(48, 64), 256, 0, stream>>>(xb, wqb, ct, st, Q, Kb, Vt);
    attn<<<dim3(32, 32), 256, 0, stream>>>(Q, Kb, Vt, Cc);
    gemm_out<<<dim3(16, 64), 256, 0, stream>>>(Cc, wob, out);
}